// Round 5
// baseline (104.667 us; speedup 1.0000x reference)
//
#include <hip/hip_runtime.h>

#define EMBED_DIM   2048
#define ROW_INTS    1024   // packed bytes per vocab row, harness stores one per int32
#define NUM_BLOCKS  32     // EMBED_DIM / 64 absmax blocks per row
#define TOK_PER_BLK 4      // one wave64 per token, 256-thread blocks

typedef float floatx4 __attribute__((ext_vector_type(4)));
typedef int   intx4   __attribute__((ext_vector_type(4)));

// NF4 codebook (bitsandbytes normal-float-4)
__constant__ float NF4_LUT_C[16] = {
    -1.0f, -0.6961928009986877f, -0.5250730514526367f, -0.39491748809814453f,
    -0.28444138169288635f, -0.18477343022823334f, -0.09105003625154495f, 0.0f,
    0.07958029955625534f, 0.16093020141124725f, 0.24611230194568634f,
    0.33791524171829224f, 0.44070982933044434f, 0.5626170039176941f,
    0.7229568362236023f, 1.0f
};

__global__ __launch_bounds__(256) void nf4_embed_kernel(
    const int* __restrict__ ids,
    const int* __restrict__ packed,   // one packed byte (0..255) per int32
    const float* __restrict__ absmax,
    float* __restrict__ out,          // fp16-valued reference, f32 buffer
    int n_tokens)
{
    // 16-entry LUT in LDS: 16 distinct banks, one address per bank ->
    // random wave64 reads are broadcast, conflict-free by construction.
    __shared__ float lut[16];
    if (threadIdx.x < 16) lut[threadIdx.x] = NF4_LUT_C[threadIdx.x];
    __syncthreads();

    const int wave = threadIdx.x >> 6;   // token within block
    const int lane = threadIdx.x & 63;
    const int n = blockIdx.x * TOK_PER_BLK + wave;
    if (n >= n_tokens) return;

    const int tok = ids[n];
    const int*   prow  = packed + (size_t)tok * ROW_INTS;
    const float* amrow = absmax + (size_t)tok * NUM_BLOCKS;
    float*       orow  = out    + (size_t)n   * EMBED_DIM;

    // chunk c: lane l covers output elements [l*8 + c*512, +8)
    //   packed int32s: idx l*4 + c*256, 4 of them (wave-contiguous 1KiB load)
    //   absmax block:  (l*8 + c*512)/64 = l/8 + c*8 (constant over the 8)
    //   store: 32B at element l*8 + c*512 (wave-contiguous 2KiB store)
    #pragma unroll
    for (int c = 0; c < 4; ++c) {
        const intx4 pk = *(const intx4*)(prow + lane * 4 + c * 256);
        const float am = amrow[(lane >> 3) + c * 8];

        alignas(16) float v[8];
        #pragma unroll
        for (int k = 0; k < 4; ++k) {
            const unsigned int b = (unsigned int)pk[k] & 0xFFu;
            // high nibble is the first element of the pair
            v[2 * k]     = lut[b >> 4]  * am;
            v[2 * k + 1] = lut[b & 15u] * am;
        }
        // nontemporal: don't let the 256MB output stream pollute L2/L3;
        // the gathered weight rows get whatever cache residency remains.
        float* obase = orow + (size_t)lane * 8 + (size_t)c * 512;
        __builtin_nontemporal_store(*(const floatx4*)&v[0], (floatx4*)obase);
        __builtin_nontemporal_store(*(const floatx4*)&v[4], (floatx4*)(obase + 4));
    }
}

extern "C" void kernel_launch(void* const* d_in, const int* in_sizes, int n_in,
                              void* d_out, int out_size, void* d_ws, size_t ws_size,
                              hipStream_t stream) {
    const int*   ids    = (const int*)d_in[0];
    const int*   packed = (const int*)d_in[1];
    const float* amax   = (const float*)d_in[2];
    float*       out    = (float*)d_out;

    const int n_tokens = in_sizes[0];                 // 4*8192 = 32768
    const int blocks   = (n_tokens + TOK_PER_BLK - 1) / TOK_PER_BLK;

    nf4_embed_kernel<<<blocks, 256, 0, stream>>>(ids, packed, amax, out, n_tokens);
}

// Round 7
// 63.869 us; speedup vs baseline: 1.6388x; 1.6388x over previous
//
#include <hip/hip_runtime.h>

#define EMBED_DIM   2048
#define ROW_INTS    1024   // packed bytes per vocab row, harness stores one per int32
#define NUM_BLOCKS  32     // EMBED_DIM / 64 absmax blocks per row
#define TOK_PER_BLK 4      // one wave64 per token, 256-thread blocks

typedef float floatx4 __attribute__((ext_vector_type(4)));
typedef int   intx2   __attribute__((ext_vector_type(2)));

// NF4 codebook (bitsandbytes normal-float-4)
__constant__ float NF4_LUT_C[16] = {
    -1.0f, -0.6961928009986877f, -0.5250730514526367f, -0.39491748809814453f,
    -0.28444138169288635f, -0.18477343022823334f, -0.09105003625154495f, 0.0f,
    0.07958029955625534f, 0.16093020141124725f, 0.24611230194568634f,
    0.33791524171829224f, 0.44070982933044434f, 0.5626170039176941f,
    0.7229568362236023f, 1.0f
};

__global__ __launch_bounds__(256) void nf4_embed_kernel(
    const int* __restrict__ ids,
    const int* __restrict__ packed,   // one packed byte (0..255) per int32
    const float* __restrict__ absmax,
    float* __restrict__ out,
    int n_tokens)
{
    // 16-entry LUT in LDS: 16 distinct banks, one address per bank ->
    // random wave64 reads are broadcast, conflict-free by construction.
    __shared__ float lut[16];
    if (threadIdx.x < 16) lut[threadIdx.x] = NF4_LUT_C[threadIdx.x];
    __syncthreads();

    const int wave = threadIdx.x >> 6;   // token within block
    const int lane = threadIdx.x & 63;
    const int n = blockIdx.x * TOK_PER_BLK + wave;
    if (n >= n_tokens) return;

    const int tok = ids[n];
    const int*   prow  = packed + (size_t)tok * ROW_INTS;
    const float* amrow = absmax + (size_t)tok * NUM_BLOCKS;
    float*       orow  = out    + (size_t)n   * EMBED_DIM;

    // (c,s) subchunk: lane l covers output elements e0 = c*512 + s*256 + l*4
    //   packed ints:  2 at idx e0/2 = c*256 + s*128 + l*2  (512B/wave contiguous)
    //   absmax block: e0/64 = c*8 + s*4 + l/16             (constant over the 4)
    //   store: ONE float4 at e0 -> 64 lanes x 16B = 1KiB contiguous,
    //          16 complete 64B lines per instruction (full-line nt writes,
    //          no partial-line write amplification).
    #pragma unroll
    for (int c = 0; c < 4; ++c) {
        #pragma unroll
        for (int s = 0; s < 2; ++s) {
            const intx2 pk = *(const intx2*)(prow + c * 256 + s * 128 + lane * 2);
            const float am = amrow[c * 8 + s * 4 + (lane >> 4)];

            const unsigned int b0 = (unsigned int)pk.x & 0xFFu;
            const unsigned int b1 = (unsigned int)pk.y & 0xFFu;
            floatx4 v;
            // high nibble is the first element of the pair
            v.x = lut[b0 >> 4]  * am;
            v.y = lut[b0 & 15u] * am;
            v.z = lut[b1 >> 4]  * am;
            v.w = lut[b1 & 15u] * am;

            // nontemporal: output is write-once, never reread; full-line
            // stores keep HBM write efficiency at 100%.
            __builtin_nontemporal_store(
                v, (floatx4*)(orow + c * 512 + s * 256 + lane * 4));
        }
    }
}

extern "C" void kernel_launch(void* const* d_in, const int* in_sizes, int n_in,
                              void* d_out, int out_size, void* d_ws, size_t ws_size,
                              hipStream_t stream) {
    const int*   ids    = (const int*)d_in[0];
    const int*   packed = (const int*)d_in[1];
    const float* amax   = (const float*)d_in[2];
    float*       out    = (float*)d_out;

    const int n_tokens = in_sizes[0];                 // 4*8192 = 32768
    const int blocks   = (n_tokens + TOK_PER_BLK - 1) / TOK_PER_BLK;

    nf4_embed_kernel<<<blocks, 256, 0, stream>>>(ids, packed, amax, out, n_tokens);
}